// Round 7
// baseline (654.300 us; speedup 1.0000x reference)
//
#include <hip/hip_runtime.h>
#include <stdint.h>

typedef __bf16 bf16;
typedef bf16 bf16x4 __attribute__((ext_vector_type(4)));
typedef bf16 bf16x8 __attribute__((ext_vector_type(8)));
typedef float f32x4 __attribute__((ext_vector_type(4)));

// Inputs fp32, output fp32 (settled round 4). Internal: bf16 MFMA, fp32 acc.
// Q is pre-scaled by 0.125*log2(e) in the QKV epilogue so attention softmax
// is exp2(s) with zero extra VALU per element.

// Async global->LDS, 16B/lane; LDS dest = wave-uniform base + lane*16 [m97].
__device__ __forceinline__ void gll16(const bf16* g, const bf16* l) {
  __builtin_amdgcn_global_load_lds(
      (__attribute__((address_space(1))) void*)(g),
      (__attribute__((address_space(3))) void*)(l),
      16, 0, 0);
}

// ---------------- LayerNorm: one block per row of 1024, fp32 in -> bf16 out ----------------
__global__ __launch_bounds__(256) void ln_kernel(
    const float* __restrict__ x, const float* __restrict__ gamma,
    const float* __restrict__ beta, bf16* __restrict__ xn)
{
  __shared__ float red[8];
  const long row = blockIdx.x;
  const int t = threadIdx.x;
  f32x4 f = *(const f32x4*)(x + row * 1024 + t * 4);
  float sum = f[0] + f[1] + f[2] + f[3];
  float sq  = f[0]*f[0] + f[1]*f[1] + f[2]*f[2] + f[3]*f[3];
#pragma unroll
  for (int sh = 1; sh < 64; sh <<= 1) {
    sum += __shfl_xor(sum, sh, 64);
    sq  += __shfl_xor(sq,  sh, 64);
  }
  const int wave = t >> 6, lane = t & 63;
  if (lane == 0) { red[wave] = sum; red[wave + 4] = sq; }
  __syncthreads();
  sum = red[0] + red[1] + red[2] + red[3];
  sq  = red[4] + red[5] + red[6] + red[7];
  const float mu  = sum * (1.0f / 1024.0f);
  const float var = sq * (1.0f / 1024.0f) - mu * mu;
  const float rs  = rsqrtf(var + 1e-5f);
  f32x4 g = *(const f32x4*)(gamma + t * 4);
  f32x4 bb = *(const f32x4*)(beta + t * 4);
  bf16x4 ov;
#pragma unroll
  for (int i = 0; i < 4; i++)
    ov[i] = (bf16)((f[i] - mu) * rs * g[i] + bb[i]);
  *(bf16x4*)(xn + row * 1024 + t * 4) = ov;
}

// ---------------- Weight transpose: out[c][r] = (bf16)in[r][c], fp32 in ----------------
__global__ __launch_bounds__(256) void transpose_kernel(
    const float* __restrict__ in, bf16* __restrict__ out, int R, int Cc)
{
  __shared__ bf16 tile[32][33];
  const int c0 = blockIdx.x * 32, r0 = blockIdx.y * 32;
  const int tx = threadIdx.x & 31, ty = threadIdx.x >> 5;
#pragma unroll
  for (int i = 0; i < 32; i += 8)
    tile[ty + i][tx] = (bf16)in[(long)(r0 + ty + i) * Cc + c0 + tx];
  __syncthreads();
#pragma unroll
  for (int i = 0; i < 32; i += 8)
    out[(long)(c0 + ty + i) * R + r0 + tx] = tile[tx][ty + i];
}

// ---------------- GEMM: C[m][n] = sum_k A[m][k] * BT[n][k] + bias[n] ----------------
// m97 structure: 128x128 tile, BK=32, 4 waves each 64x64, global_load_lds x16.
// mode 0: store C [M][N] fp32. mode 1: QKV scatter bf16 (q/k [bh][l][64], v->vt [bh][64][l]);
//   Q is additionally scaled by 0.125*log2(e) for the exp2-softmax in attn.
__global__ __launch_bounds__(256, 2) void gemm_bt(
    const bf16* __restrict__ A, const bf16* __restrict__ BT,
    const float* __restrict__ bias, float* __restrict__ C,
    bf16* __restrict__ qb, bf16* __restrict__ kb, bf16* __restrict__ vtb,
    int K, int N, int mode)
{
  __shared__ bf16 sA[128 * 32];
  __shared__ bf16 sB[128 * 32];
  const int t = threadIdx.x;
  const int lane = t & 63;
  const int wave = t >> 6;
  const int wave_u = __builtin_amdgcn_readfirstlane(wave);
  const int quad = lane >> 4;
  const int c16 = lane & 15;
  const int wm = (wave >> 1) * 64;
  const int wn = (wave & 1) * 64;
  const int m0 = blockIdx.x * 128;
  const int n0 = blockIdx.y * 128;

  f32x4 acc[4][4] = {};

  const int srow = t >> 2;          // 0..63
  const int scol = (t & 3) * 8;     // 0,8,16,24
  const bf16* gA = A + (long)(m0 + srow) * K + scol;
  const bf16* gB = BT + (long)(n0 + srow) * K + scol;
  const bf16* lA = sA + wave_u * 512;
  const bf16* lB = sB + wave_u * 512;
  const long rowskip = (long)64 * K;

  for (int k0 = 0; k0 < K; k0 += 32) {
    gll16(gA + k0, lA);
    gll16(gA + k0 + rowskip, lA + 2048);
    gll16(gB + k0, lB);
    gll16(gB + k0 + rowskip, lB + 2048);
    __syncthreads();
    bf16x8 af[4], bfr[4];
#pragma unroll
    for (int i = 0; i < 4; i++)
      af[i] = *(const bf16x8*)(sA + (wm + i * 16 + c16) * 32 + quad * 8);
#pragma unroll
    for (int j = 0; j < 4; j++)
      bfr[j] = *(const bf16x8*)(sB + (wn + j * 16 + c16) * 32 + quad * 8);
#pragma unroll
    for (int i = 0; i < 4; i++)
#pragma unroll
      for (int j = 0; j < 4; j++)
        acc[i][j] = __builtin_amdgcn_mfma_f32_16x16x32_bf16(af[i], bfr[j], acc[i][j], 0, 0, 0);
    __syncthreads();
  }

  // C/D layout: col = lane&15, row = quad*4 + reg   [verified m89/m91]
#pragma unroll
  for (int i = 0; i < 4; i++) {
    const int mbase = m0 + wm + i * 16 + quad * 4;
#pragma unroll
    for (int j = 0; j < 4; j++) {
      const int n = n0 + wn + j * 16 + c16;
      const float bv = bias[n];
      if (mode == 0) {
#pragma unroll
        for (int r = 0; r < 4; r++)
          C[(long)(mbase + r) * N + n] = acc[i][j][r] + bv;
      } else {
        const int part = n >> 10;       // 0=Q 1=K 2=V
        const int inner = n & 1023;
        const int h = inner >> 6, d = inner & 63;
#pragma unroll
        for (int r = 0; r < 4; r++) {
          const int m = mbase + r;
          const int b = m >> 11, l = m & 2047;
          const long bh = (long)((b << 4) | h);
          const float v = acc[i][j][r] + bv;
          if (part == 0)      qb [(bh * 2048 + l) * 64 + d] = (bf16)(v * 0.18033688f); // 0.125*log2e
          else if (part == 1) kb [(bh * 2048 + l) * 64 + d] = (bf16)v;
          else                vtb[(bh * 64 + d) * 2048 + l] = (bf16)v;
        }
      }
    }
  }
}

// ---------------- Flash attention: block = (bh, 64-row Q tile), KV tile 128 ----------------
// BARRIER-FREE main loop: K and V B-fragments are read directly from global
// (16B contiguous per lane; L1 absorbs the 4x intra-block wave redundancy,
// L2 the cross-block redundancy). Only LDS use is the per-wave-private P
// C-layout -> A-layout round trip (same-wave ds ordering, verified r5/r6).
// LDS traffic drops 192KB -> 32KB per block-iter; zero __syncthreads in loop.
// Softmax: p = exp2(s) with Q pre-scaled; row-sum deferred to one end reduce.
__global__ __launch_bounds__(256, 4) void attn_kernel(
    const bf16* __restrict__ q, const bf16* __restrict__ k,
    const bf16* __restrict__ vt, bf16* __restrict__ att)
{
  __shared__ bf16 sP[4][16 * 132];   // per-wave P[16][128], stride 132 (66 words, mod32=2)

  const int bh = blockIdx.y;
  const int b = bh >> 4, h = bh & 15;
  const int q0 = blockIdx.x * 64;
  const int t = threadIdx.x;
  const int wave = t >> 6, lane = t & 63;
  const int quad = lane >> 4, c16 = lane & 15;

  const bf16* qp = q + (long)bh * (2048 * 64);
  const bf16* kp = k + (long)bh * (2048 * 64);
  const bf16* vp = vt + (long)bh * (64 * 2048);

  // Q fragment direct from global: A[m=c16][k=quad*8+j] (loop-invariant)
  const bf16* qrow = qp + (long)(q0 + wave * 16 + c16) * 64 + quad * 8;
  const bf16x8 aq0 = *(const bf16x8*)(qrow);
  const bf16x8 aq1 = *(const bf16x8*)(qrow + 32);

  // loop-invariant row bases
  const bf16* krow = kp + (long)c16 * 64 + quad * 8;        // + (kv0 + j*16)*64
  const bf16* vrow0 = vp + (long)c16 * 2048 + quad * 8;     // + j*16*2048 + kv0 + ks*32
  bf16* pw = &sP[wave][0];

  float p_sum[4] = {0.0f, 0.0f, 0.0f, 0.0f};
  f32x4 o_acc[4] = {};

  for (int kt = 0; kt < 16; kt++) {
    const int kv0 = kt * 128;

    // S = Q K^T : wave's 16 q-rows x 128 kv-cols; K B-frags straight from global
    f32x4 s[8];
#pragma unroll
    for (int j = 0; j < 8; j++) {
      const bf16* kb2 = krow + (long)(kv0 + j * 16) * 64;
      bf16x8 bk0 = *(const bf16x8*)(kb2);
      bf16x8 bk1 = *(const bf16x8*)(kb2 + 32);
      f32x4 z = {};
      z = __builtin_amdgcn_mfma_f32_16x16x32_bf16(aq0, bk0, z, 0, 0, 0);
      z = __builtin_amdgcn_mfma_f32_16x16x32_bf16(aq1, bk1, z, 0, 0, 0);
      s[j] = z;
    }

    // p = exp2(s) (Q pre-scaled); per-lane row partial sums
#pragma unroll
    for (int j = 0; j < 8; j++) {
#pragma unroll
      for (int r = 0; r < 4; r++) {
        const float p = __builtin_amdgcn_exp2f(s[j][r]);
        s[j][r] = p;
        p_sum[r] += p;
      }
    }

    // P into private sP[16][132] (C-layout scatter; same-wave ds order)
#pragma unroll
    for (int j = 0; j < 8; j++)
#pragma unroll
      for (int r = 0; r < 4; r++)
        pw[(quad * 4 + r) * 132 + j * 16 + c16] = (bf16)s[j][r];

    // O += P @ V : A = own-wave sP rows; V B-frags straight from global
#pragma unroll
    for (int ks = 0; ks < 4; ks++) {
      bf16x8 ap = *(const bf16x8*)&pw[c16 * 132 + ks * 32 + quad * 8];
#pragma unroll
      for (int j = 0; j < 4; j++) {
        bf16x8 bv2 = *(const bf16x8*)(vrow0 + (long)(j * 16) * 2048 + kv0 + ks * 32);
        o_acc[j] = __builtin_amdgcn_mfma_f32_16x16x32_bf16(ap, bv2, o_acc[j], 0, 0, 0);
      }
    }
  }

  // final row-sum reduce across the 16-lane c16 group
#pragma unroll
  for (int r = 0; r < 4; r++) {
#pragma unroll
    for (int sh = 1; sh <= 8; sh <<= 1) p_sum[r] += __shfl_xor(p_sum[r], sh, 64);
  }

  // epilogue: att[b][l][h*64+d]
  const int gl0 = q0 + wave * 16 + quad * 4;
#pragma unroll
  for (int j = 0; j < 4; j++) {
    const int d = j * 16 + c16;
#pragma unroll
    for (int r = 0; r < 4; r++) {
      const float ov = o_acc[j][r] / p_sum[r];
      att[((long)b * 2048 + gl0 + r) * 1024 + h * 64 + d] = (bf16)ov;
    }
  }
}

// ---------------- launcher ----------------
extern "C" void kernel_launch(void* const* d_in, const int* in_sizes, int n_in,
                              void* d_out, int out_size, void* d_ws, size_t ws_size,
                              hipStream_t stream) {
  (void)in_sizes; (void)n_in; (void)out_size; (void)ws_size;
  const float* x     = (const float*)d_in[0];
  const float* w_qkv = (const float*)d_in[1];
  const float* b_qkv = (const float*)d_in[2];
  const float* w_out = (const float*)d_in[3];
  const float* b_out = (const float*)d_in[4];
  const float* gamma = (const float*)d_in[5];
  const float* beta  = (const float*)d_in[6];
  float* out = (float*)d_out;
  bf16* ws  = (bf16*)d_ws;

  // ws layout (bf16 elems), total 37.75M elems = 75.5 MB
  bf16* xn    = ws;                    // 8192*1024 (reused as att buffer)
  bf16* wqkvT = ws + 8388608;          // 3072*1024
  bf16* woutT = wqkvT + 3145728;       // 1024*1024
  bf16* qbuf  = woutT + 1048576;       // 8192*1024
  bf16* kbuf  = qbuf + 8388608;        // 8192*1024
  bf16* vtbuf = kbuf + 8388608;        // 8192*1024
  bf16* att   = xn;                    // alias: xn dead after QKV GEMM

  transpose_kernel<<<dim3(3072 / 32, 1024 / 32), 256, 0, stream>>>(w_qkv, wqkvT, 1024, 3072);
  transpose_kernel<<<dim3(1024 / 32, 1024 / 32), 256, 0, stream>>>(w_out, woutT, 1024, 1024);
  ln_kernel<<<dim3(8192), 256, 0, stream>>>(x, gamma, beta, xn);
  gemm_bt<<<dim3(8192 / 128, 3072 / 128), 256, 0, stream>>>(
      xn, wqkvT, b_qkv, (float*)nullptr, qbuf, kbuf, vtbuf, 1024, 3072, 1);
  attn_kernel<<<dim3(2048 / 64, 64), 256, 0, stream>>>(qbuf, kbuf, vtbuf, att);
  gemm_bt<<<dim3(8192 / 128, 1024 / 128), 256, 0, stream>>>(
      att, woutT, b_out, out, (bf16*)nullptr, (bf16*)nullptr, (bf16*)nullptr, 1024, 1024, 0);
}

// Round 8
// 444.717 us; speedup vs baseline: 1.4713x; 1.4713x over previous
//
#include <hip/hip_runtime.h>
#include <stdint.h>

typedef __bf16 bf16;
typedef bf16 bf16x4 __attribute__((ext_vector_type(4)));
typedef bf16 bf16x8 __attribute__((ext_vector_type(8)));
typedef float f32x4 __attribute__((ext_vector_type(4)));

// Inputs fp32, output fp32 (settled round 4). Internal: bf16 MFMA, fp32 acc.
// Q pre-scaled by 0.125*log2(e) in QKV epilogue -> softmax is raw exp2.

// Async global->LDS, 16B/lane; LDS dest = wave-uniform base + lane*16 [m97].
__device__ __forceinline__ void gll16(const bf16* g, const bf16* l) {
  __builtin_amdgcn_global_load_lds(
      (__attribute__((address_space(1))) void*)(g),
      (__attribute__((address_space(3))) void*)(l),
      16, 0, 0);
}

// ---------------- LayerNorm: one block per row of 1024, fp32 in -> bf16 out ----------------
__global__ __launch_bounds__(256) void ln_kernel(
    const float* __restrict__ x, const float* __restrict__ gamma,
    const float* __restrict__ beta, bf16* __restrict__ xn)
{
  __shared__ float red[8];
  const long row = blockIdx.x;
  const int t = threadIdx.x;
  f32x4 f = *(const f32x4*)(x + row * 1024 + t * 4);
  float sum = f[0] + f[1] + f[2] + f[3];
  float sq  = f[0]*f[0] + f[1]*f[1] + f[2]*f[2] + f[3]*f[3];
#pragma unroll
  for (int sh = 1; sh < 64; sh <<= 1) {
    sum += __shfl_xor(sum, sh, 64);
    sq  += __shfl_xor(sq,  sh, 64);
  }
  const int wave = t >> 6, lane = t & 63;
  if (lane == 0) { red[wave] = sum; red[wave + 4] = sq; }
  __syncthreads();
  sum = red[0] + red[1] + red[2] + red[3];
  sq  = red[4] + red[5] + red[6] + red[7];
  const float mu  = sum * (1.0f / 1024.0f);
  const float var = sq * (1.0f / 1024.0f) - mu * mu;
  const float rs  = rsqrtf(var + 1e-5f);
  f32x4 g = *(const f32x4*)(gamma + t * 4);
  f32x4 bb = *(const f32x4*)(beta + t * 4);
  bf16x4 ov;
#pragma unroll
  for (int i = 0; i < 4; i++)
    ov[i] = (bf16)((f[i] - mu) * rs * g[i] + bb[i]);
  *(bf16x4*)(xn + row * 1024 + t * 4) = ov;
}

// ---------------- Weight transpose: out[c][r] = (bf16)in[r][c], fp32 in ----------------
__global__ __launch_bounds__(256) void transpose_kernel(
    const float* __restrict__ in, bf16* __restrict__ out, int R, int Cc)
{
  __shared__ bf16 tile[32][33];
  const int c0 = blockIdx.x * 32, r0 = blockIdx.y * 32;
  const int tx = threadIdx.x & 31, ty = threadIdx.x >> 5;
#pragma unroll
  for (int i = 0; i < 32; i += 8)
    tile[ty + i][tx] = (bf16)in[(long)(r0 + ty + i) * Cc + c0 + tx];
  __syncthreads();
#pragma unroll
  for (int i = 0; i < 32; i += 8)
    out[(long)(c0 + ty + i) * R + r0 + tx] = tile[tx][ty + i];
}

// ---------------- GEMM: C[m][n] = sum_k A[m][k] * BT[n][k] + bias[n] ----------------
// m97 structure: 128x128 tile, BK=32, 4 waves each 64x64, global_load_lds x16.
// mode 0: store C [M][N] fp32. mode 1: QKV scatter bf16 (q/k [bh][l][64], v->vt [bh][64][l]);
//   Q additionally scaled by 0.125*log2(e).
__global__ __launch_bounds__(256, 2) void gemm_bt(
    const bf16* __restrict__ A, const bf16* __restrict__ BT,
    const float* __restrict__ bias, float* __restrict__ C,
    bf16* __restrict__ qb, bf16* __restrict__ kb, bf16* __restrict__ vtb,
    int K, int N, int mode)
{
  __shared__ bf16 sA[128 * 32];
  __shared__ bf16 sB[128 * 32];
  const int t = threadIdx.x;
  const int lane = t & 63;
  const int wave = t >> 6;
  const int wave_u = __builtin_amdgcn_readfirstlane(wave);
  const int quad = lane >> 4;
  const int c16 = lane & 15;
  const int wm = (wave >> 1) * 64;
  const int wn = (wave & 1) * 64;
  const int m0 = blockIdx.x * 128;
  const int n0 = blockIdx.y * 128;

  f32x4 acc[4][4] = {};

  const int srow = t >> 2;          // 0..63
  const int scol = (t & 3) * 8;     // 0,8,16,24
  const bf16* gA = A + (long)(m0 + srow) * K + scol;
  const bf16* gB = BT + (long)(n0 + srow) * K + scol;
  const bf16* lA = sA + wave_u * 512;
  const bf16* lB = sB + wave_u * 512;
  const long rowskip = (long)64 * K;

  for (int k0 = 0; k0 < K; k0 += 32) {
    gll16(gA + k0, lA);
    gll16(gA + k0 + rowskip, lA + 2048);
    gll16(gB + k0, lB);
    gll16(gB + k0 + rowskip, lB + 2048);
    __syncthreads();
    bf16x8 af[4], bfr[4];
#pragma unroll
    for (int i = 0; i < 4; i++)
      af[i] = *(const bf16x8*)(sA + (wm + i * 16 + c16) * 32 + quad * 8);
#pragma unroll
    for (int j = 0; j < 4; j++)
      bfr[j] = *(const bf16x8*)(sB + (wn + j * 16 + c16) * 32 + quad * 8);
#pragma unroll
    for (int i = 0; i < 4; i++)
#pragma unroll
      for (int j = 0; j < 4; j++)
        acc[i][j] = __builtin_amdgcn_mfma_f32_16x16x32_bf16(af[i], bfr[j], acc[i][j], 0, 0, 0);
    __syncthreads();
  }

  // C/D layout: col = lane&15, row = quad*4 + reg   [verified m89/m91]
#pragma unroll
  for (int i = 0; i < 4; i++) {
    const int mbase = m0 + wm + i * 16 + quad * 4;
#pragma unroll
    for (int j = 0; j < 4; j++) {
      const int n = n0 + wn + j * 16 + c16;
      const float bv = bias[n];
      if (mode == 0) {
#pragma unroll
        for (int r = 0; r < 4; r++)
          C[(long)(mbase + r) * N + n] = acc[i][j][r] + bv;
      } else {
        const int part = n >> 10;       // 0=Q 1=K 2=V
        const int inner = n & 1023;
        const int h = inner >> 6, d = inner & 63;
#pragma unroll
        for (int r = 0; r < 4; r++) {
          const int m = mbase + r;
          const int b = m >> 11, l = m & 2047;
          const long bh = (long)((b << 4) | h);
          const float v = acc[i][j][r] + bv;
          if (part == 0)      qb [(bh * 2048 + l) * 64 + d] = (bf16)(v * 0.18033688f); // 0.125*log2e
          else if (part == 1) kb [(bh * 2048 + l) * 64 + d] = (bf16)v;
          else                vtb[(bh * 64 + d) * 2048 + l] = (bf16)v;
        }
      }
    }
  }
}

// ---------------- Flash attention ----------------
// Block = (bh, 64 q-rows); wave (wq,wkv) owns 32 q-rows x 64-kv slice.
// NO barriers in the main loop: K/V B-frags are wave-disjoint -> direct global
// reads, explicitly prefetched into register arrays (r7 lesson: unnamed inline
// loads get serialized; named arrays force batched issue). Only LDS use in the
// loop is the wave-private P C->A round trip (same-wave ds order, verified r5/r6).
// End: one cross-wave partial-O/psum reduction (wkv pairs) via LDS, 2 barriers.
__global__ __launch_bounds__(256, 3) void attn_kernel(
    const bf16* __restrict__ q, const bf16* __restrict__ k,
    const bf16* __restrict__ vt, bf16* __restrict__ att)
{
  __shared__ bf16 sP[4][32 * 68];   // per-wave P[32 q][64 kv] stride 68; aliased for O-reduce

  const int bh = blockIdx.y;
  const int b = bh >> 4, h = bh & 15;
  const int q0 = blockIdx.x * 64;
  const int t = threadIdx.x;
  const int wave = t >> 6, lane = t & 63;
  const int quad = lane >> 4, c16 = lane & 15;
  const int wq = wave >> 1, wkv = wave & 1;

  const bf16* qp = q + (long)bh * (2048 * 64);
  const bf16* kp = k + (long)bh * (2048 * 64);
  const bf16* vp = vt + (long)bh * (64 * 2048);

  // Q A-frags (loop-invariant): rows q0 + wq*32 + m*16 + c16, k = kk*32 + quad*8
  bf16x8 aq[2][2];
#pragma unroll
  for (int m = 0; m < 2; m++)
#pragma unroll
    for (int kk = 0; kk < 2; kk++)
      aq[m][kk] = *(const bf16x8*)(qp + (long)(q0 + wq * 32 + m * 16 + c16) * 64 + kk * 32 + quad * 8);

  // K B-frag base: row kv = kt*128 + wkv*64 + j*16 + c16, k = kk*32 + quad*8
  const bf16* kbase = kp + (long)(wkv * 64 + c16) * 64 + quad * 8;
  // V B-frag base: Vt[d = j*16 + c16][kt*128 + wkv*64 + ks*32 + quad*8]
  const bf16* vbase = vp + (long)c16 * 2048 + wkv * 64 + quad * 8;

  bf16* pw = &sP[wave][0];

  f32x4 o_acc[2][4] = {};
  float p_sum[2][4] = {{0,0,0,0},{0,0,0,0}};

  // prefetch K frags for kt=0
  bf16x8 kreg[4][2];
#pragma unroll
  for (int j = 0; j < 4; j++)
#pragma unroll
    for (int kk = 0; kk < 2; kk++)
      kreg[j][kk] = *(const bf16x8*)(kbase + (long)j * 1024 + kk * 32);

  for (int kt = 0; kt < 16; kt++) {
    const int kv0 = kt * 128;

    // QK: S[2m][4j] over wave's 64-kv slice
    f32x4 s[2][4];
#pragma unroll
    for (int m = 0; m < 2; m++)
#pragma unroll
      for (int j = 0; j < 4; j++) {
        f32x4 z = {};
        z = __builtin_amdgcn_mfma_f32_16x16x32_bf16(aq[m][0], kreg[j][0], z, 0, 0, 0);
        z = __builtin_amdgcn_mfma_f32_16x16x32_bf16(aq[m][1], kreg[j][1], z, 0, 0, 0);
        s[m][j] = z;
      }

    // prefetch next iter's K frags (latency hidden under exp + P store + PV)
    const long kvoffn = (long)((kt + 1) & 15) * 8192;
#pragma unroll
    for (int j = 0; j < 4; j++)
#pragma unroll
      for (int kk = 0; kk < 2; kk++)
        kreg[j][kk] = *(const bf16x8*)(kbase + kvoffn + (long)j * 1024 + kk * 32);

    // V frags for current iter (issued ~400 cycles before PV use)
    bf16x8 vreg[4][2];
#pragma unroll
    for (int j = 0; j < 4; j++)
#pragma unroll
      for (int ks = 0; ks < 2; ks++)
        vreg[j][ks] = *(const bf16x8*)(vbase + (long)j * 32768 + kv0 + ks * 32);

    // p = exp2(s); per-lane row partials; P -> wave-private LDS (C-layout scatter)
#pragma unroll
    for (int m = 0; m < 2; m++)
#pragma unroll
      for (int j = 0; j < 4; j++)
#pragma unroll
        for (int r = 0; r < 4; r++) {
          const float p = __builtin_amdgcn_exp2f(s[m][j][r]);
          p_sum[m][r] += p;
          pw[(m * 16 + quad * 4 + r) * 68 + j * 16 + c16] = (bf16)p;
        }

    // PV: O_partial[2m][4j] += P[2m][64] * V[64][4j]
#pragma unroll
    for (int ks = 0; ks < 2; ks++) {
      bf16x8 ap[2];
#pragma unroll
      for (int m = 0; m < 2; m++)
        ap[m] = *(const bf16x8*)&pw[(m * 16 + c16) * 68 + ks * 32 + quad * 8];
#pragma unroll
      for (int j = 0; j < 4; j++)
#pragma unroll
        for (int m = 0; m < 2; m++)
          o_acc[m][j] = __builtin_amdgcn_mfma_f32_16x16x32_bf16(ap[m], vreg[j][ks], o_acc[m][j], 0, 0, 0);
    }
  }

  // reduce p_sum across the 16-lane c16 group (quad preserved)
#pragma unroll
  for (int m = 0; m < 2; m++)
#pragma unroll
    for (int r = 0; r < 4; r++)
#pragma unroll
      for (int sh = 1; sh <= 8; sh <<= 1)
        p_sum[m][r] += __shfl_xor(p_sum[m][r], sh, 64);

  // cross-wave (wkv) reduction via LDS (aliases sP; all sP reads are done)
  float* Ored = (float*)&sP[0][0];          // [2 wq][32 row][65] fp32
  float* Pred = Ored + 2 * 32 * 65;         // [2 wq][32] fp32
  __syncthreads();
  if (wkv == 1) {
#pragma unroll
    for (int m = 0; m < 2; m++) {
#pragma unroll
      for (int j = 0; j < 4; j++)
#pragma unroll
        for (int r = 0; r < 4; r++)
          Ored[(wq * 32 + m * 16 + quad * 4 + r) * 65 + j * 16 + c16] = o_acc[m][j][r];
      if (c16 == 0)
#pragma unroll
        for (int r = 0; r < 4; r++)
          Pred[wq * 32 + m * 16 + quad * 4 + r] = p_sum[m][r];
    }
  }
  __syncthreads();
  if (wkv == 0) {
#pragma unroll
    for (int m = 0; m < 2; m++) {
      float ps[4];
#pragma unroll
      for (int r = 0; r < 4; r++)
        ps[r] = p_sum[m][r] + Pred[wq * 32 + m * 16 + quad * 4 + r];
#pragma unroll
      for (int j = 0; j < 4; j++)
#pragma unroll
        for (int r = 0; r < 4; r++) {
          const float ov = (o_acc[m][j][r] +
                            Ored[(wq * 32 + m * 16 + quad * 4 + r) * 65 + j * 16 + c16]) / ps[r];
          att[((long)b * 2048 + q0 + wq * 32 + m * 16 + quad * 4 + r) * 1024 + h * 64 + j * 16 + c16] = (bf16)ov;
        }
    }
  }
}

// ---------------- launcher ----------------
extern "C" void kernel_launch(void* const* d_in, const int* in_sizes, int n_in,
                              void* d_out, int out_size, void* d_ws, size_t ws_size,
                              hipStream_t stream) {
  (void)in_sizes; (void)n_in; (void)out_size; (void)ws_size;
  const float* x     = (const float*)d_in[0];
  const float* w_qkv = (const float*)d_in[1];
  const float* b_qkv = (const float*)d_in[2];
  const float* w_out = (const float*)d_in[3];
  const float* b_out = (const float*)d_in[4];
  const float* gamma = (const float*)d_in[5];
  const float* beta  = (const float*)d_in[6];
  float* out = (float*)d_out;
  bf16* ws  = (bf16*)d_ws;

  // ws layout (bf16 elems), total 37.75M elems = 75.5 MB
  bf16* xn    = ws;                    // 8192*1024 (reused as att buffer)
  bf16* wqkvT = ws + 8388608;          // 3072*1024
  bf16* woutT = wqkvT + 3145728;       // 1024*1024
  bf16* qbuf  = woutT + 1048576;       // 8192*1024
  bf16* kbuf  = qbuf + 8388608;        // 8192*1024
  bf16* vtbuf = kbuf + 8388608;        // 8192*1024
  bf16* att   = xn;                    // alias: xn dead after QKV GEMM

  transpose_kernel<<<dim3(3072 / 32, 1024 / 32), 256, 0, stream>>>(w_qkv, wqkvT, 1024, 3072);
  transpose_kernel<<<dim3(1024 / 32, 1024 / 32), 256, 0, stream>>>(w_out, woutT, 1024, 1024);
  ln_kernel<<<dim3(8192), 256, 0, stream>>>(x, gamma, beta, xn);
  gemm_bt<<<dim3(8192 / 128, 3072 / 128), 256, 0, stream>>>(
      xn, wqkvT, b_qkv, (float*)nullptr, qbuf, kbuf, vtbuf, 1024, 3072, 1);
  attn_kernel<<<dim3(2048 / 64, 64), 256, 0, stream>>>(qbuf, kbuf, vtbuf, att);
  gemm_bt<<<dim3(8192 / 128, 1024 / 128), 256, 0, stream>>>(
      att, woutT, b_out, out, (bf16*)nullptr, (bf16*)nullptr, (bf16*)nullptr, 1024, 1024, 0);
}